// Round 10
// baseline (698.367 us; speedup 1.0000x reference)
//
#include <hip/hip_runtime.h>
#include <hip/hip_bf16.h>
#include <math.h>

typedef __attribute__((ext_vector_type(4))) float  f32x4;
typedef __attribute__((ext_vector_type(8))) __bf16 bf16x8;
typedef __attribute__((ext_vector_type(4))) unsigned int u32x4;

__device__ __forceinline__ unsigned short f2bu(float x) {
    __bf16 h = (__bf16)x;
    return __builtin_bit_cast(unsigned short, h);
}

__device__ __forceinline__ f32x4 MF(bf16x8 a, bf16x8 b, f32x4 c) {
    return __builtin_amdgcn_mfma_f32_16x16x32_bf16(a, b, c, 0, 0, 0);
}

__device__ __forceinline__ f32x4 zero4() { f32x4 z = {0.f, 0.f, 0.f, 0.f}; return z; }

// B-fragment from prepacked bf16 weights in global (L2-resident): 16B dwordx4
__device__ __forceinline__ bf16x8 bfragb(const unsigned short* __restrict__ w,
                                         int ldk, int row, int k0) {
    return __builtin_bit_cast(bf16x8, *(const u32x4*)(w + row * ldk + k0));
}

// ---- LDS layout (bytes), M=16 atoms/tile, two ping-pong sets ----
#define SET_SZ   20480
#define VIN_OFF  0        // 3 * 16 rows * 256B
#define H_OFF    12288    // 16 rows * 512B
#define S1_OFF   40960    // 16 rows * 256B = 4096
#define RED_OFF  45056    // 8 groups (4 waves x 2 c) * 16 f32 = 512
#define LDS_BYTES 45568

// d_ws byte offsets
#define WFOLD_BYTE 294912   // after 147456 bf16 weight elems
#define CF_BYTE    295424
#define SATOM_BYTE 295936

__device__ __forceinline__ bf16x8 afrag(const unsigned char* base, int rb, int row, int kb) {
    u32x4 q = *(const u32x4*)(base + row * rb + (kb ^ ((row & 7) << 4)));
    return __builtin_bit_cast(bf16x8, q);
}

__device__ __forceinline__ unsigned long long pack4bf(f32x4 x) {
    return (unsigned long long)f2bu(x[0])
         | ((unsigned long long)f2bu(x[1]) << 16)
         | ((unsigned long long)f2bu(x[2]) << 32)
         | ((unsigned long long)f2bu(x[3]) << 48);
}

// ---- staging (256 threads): V tile = 1536 f32x4 (6/thread), S = 512 (2/thread) ----
__device__ __forceinline__ void load_v6(const float* __restrict__ V, int t, int tid, f32x4* vld) {
    const float* p = V + (size_t)t * 6144;
#pragma unroll
    for (int j = 0; j < 6; ++j) vld[j] = *(const f32x4*)(p + ((tid + (j << 8)) << 2));
}
__device__ __forceinline__ void write_v6(unsigned char* dst, int tid, const f32x4* vld) {
#pragma unroll
    for (int j = 0; j < 6; ++j) {
        int c = tid + (j << 8);
        int row = c / 96, rem = c - row * 96;
        int d = rem >> 5, c4 = rem & 31;
        *(unsigned long long*)(dst + VIN_OFF + (d << 12) + row * 256 +
                               ((c4 << 3) ^ ((row & 7) << 4))) = pack4bf(vld[j]);
    }
}
__device__ __forceinline__ void load_s2(const float* __restrict__ S, int t, int tid, f32x4* sld) {
    const float* p = S + (size_t)t * 2048;
#pragma unroll
    for (int j = 0; j < 2; ++j) sld[j] = *(const f32x4*)(p + ((tid + (j << 8)) << 2));
}
__device__ __forceinline__ void write_s2(unsigned char* dst, int tid, const f32x4* sld) {
#pragma unroll
    for (int j = 0; j < 2; ++j) {
        int c = tid + (j << 8);
        int row = c >> 5, c4 = c & 31;
        *(unsigned long long*)(dst + H_OFF + row * 512 +
                               ((c4 << 3) ^ ((row & 7) << 4))) = pack4bf(sld[j]);
    }
}

// ---- prep: f32 weights -> bf16 frag-ready in d_ws ; fold readout ----
__global__ __launch_bounds__(256) void eqsc_prep(
    const float* __restrict__ u0w, const float* __restrict__ v0w,
    const float* __restrict__ a0w2, const float* __restrict__ v1w,
    const float* __restrict__ a0w1, const float* __restrict__ a1w1,
    const float* __restrict__ a1w2, const float* __restrict__ outw,
    const float* __restrict__ a1b2, const float* __restrict__ outbp,
    unsigned short* __restrict__ wb, float* __restrict__ wfold, float* __restrict__ cfp)
{
    int i = blockIdx.x * 256 + threadIdx.x;   // grid covers exactly 147456
    float v;
    if (i < 16384)       v = u0w[i];
    else if (i < 32768)  v = v0w[i - 16384];
    else if (i < 65536)  v = a0w2[i - 32768];   // rows 0-127 = gate, 128-255 = ss
    else if (i < 81920)  v = v1w[i - 65536];
    else if (i < 114688) v = a0w1[i - 81920];
    else                 v = a1w1[i - 114688];
    wb[i] = f2bu(v);
    if (blockIdx.x == 0 && threadIdx.x < 128) {
        float wf = 0.f;
        for (int g = 0; g < 128; ++g) wf += a1w2[g * 128 + threadIdx.x] * outw[g];
        wfold[threadIdx.x] = wf;
        if (threadIdx.x == 0) {
            float c = 0.f;
            for (int g = 0; g < 128; ++g) c += a1b2[g] * outw[g];
            cfp[0] = c + outbp[0];
        }
    }
}

__global__ __launch_bounds__(256, 3) void eqsc_main(
    const float* __restrict__ S, const float* __restrict__ V,
    const unsigned short* __restrict__ wb,
    const float* __restrict__ wfold, const float* __restrict__ cfp,
    const float* __restrict__ a0b1, const float* __restrict__ a0b2,
    const float* __restrict__ a1b1,
    float* __restrict__ sOut, int NT)
{
    __shared__ __align__(16) unsigned char lds[LDS_BYTES];
    const int tid  = threadIdx.x;
    const int lane = tid & 63;
    const int wv   = tid >> 6;       // 0..3
    const int l15  = lane & 15;
    const int lg   = lane >> 4;
    const int gA   = wv * 32 + l15;  // column group A
    const int gB   = gA + 16;        // column group B
    float* red = (float*)(lds + RED_OFF);

    const unsigned short* u0wB  = wb;
    const unsigned short* v0wB  = wb + 16384;
    const unsigned short* w2gB  = wb + 32768;
    const unsigned short* w2sB  = wb + 49152;
    const unsigned short* v1wB  = wb + 65536;
    const unsigned short* w1f0B = wb + 81920;    // ldk 256
    const unsigned short* w1f1B = wb + 114688;   // ldk 256

    const float b1_0A = a0b1[gA],       b1_0B = a0b1[gB];
    const float b2g0A = a0b2[gA],       b2g0B = a0b2[gB];
    const float b2s0A = a0b2[128 + gA], b2s0B = a0b2[128 + gB];
    const float b1_1A = a1b1[gA],       b1_1B = a1b1[gB];
    const float wfA   = wfold[gA],      wfB   = wfold[gB];
    const float cf    = cfp[0];

    const int stride = gridDim.x;
    const int t0 = blockIdx.x;

    // ---- prologue: stage tile t0 into set 0 ----
    {
        f32x4 vld[6], sld[2];
        load_v6(V, t0, tid, vld);
        load_s2(S, t0, tid, sld);
        write_v6(lds, tid, vld);
        write_s2(lds, tid, sld);
    }
    __syncthreads();

    int i = 0;
    for (int ty = t0; ty < NT + stride; ty += stride, ++i) {
        const bool yv = (ty < NT);
        const bool xv = (i > 0);
        const int  tz = ty + stride;
        const bool zv = (tz < NT);
        unsigned char* Lsy = lds + (i & 1) * SET_SZ;
        unsigned char* Lsx = lds + ((i & 1) ^ 1) * SET_SZ;

        // ======== slot 1: Y.P1 (L0 v-GEMMs) || X.P4 (L1 v-GEMM) ; issue Z loads ========
        f32x4 vldZ[6], sldZ[2];
        if (zv) { load_v6(V, tz, tid, vldZ); load_s2(S, tz, tid, sldZ); }

        f32x4 v1aA[3], v1aB[3];
        if (yv) {
            f32x4 n2A = zero4(), n2B = zero4();
#pragma unroll
            for (int d = 0; d < 3; ++d) {
                f32x4 uA = zero4(), uB = zero4(), vA = zero4(), vB = zero4();
#pragma unroll
                for (int kt = 0; kt < 4; ++kt) {
                    const int k0 = kt * 32 + lg * 8;
                    bf16x8 a = afrag(Lsy + VIN_OFF + (d << 12), 256, l15, (kt << 6) + (lg << 4));
                    uA = MF(a, bfragb(u0wB, 128, gA, k0), uA);
                    uB = MF(a, bfragb(u0wB, 128, gB, k0), uB);
                    vA = MF(a, bfragb(v0wB, 128, gA, k0), vA);
                    vB = MF(a, bfragb(v0wB, 128, gB, k0), vB);
                }
                v1aA[d] = uA; v1aB[d] = uB;
#pragma unroll
                for (int e = 0; e < 4; ++e) {
                    float xA = vA[e] + 1e-8f; n2A[e] += xA * xA;
                    float xB = vB[e] + 1e-8f; n2B[e] += xB * xB;
                }
            }
#pragma unroll
            for (int e = 0; e < 4; ++e) {
                int row = (lg << 2) + e, swz = (row & 7) << 4;
                *(unsigned short*)(Lsy + H_OFF + row * 512 + ((256 + (gA << 1)) ^ swz)) = f2bu(sqrtf(n2A[e]));
                *(unsigned short*)(Lsy + H_OFF + row * 512 + ((256 + (gB << 1)) ^ swz)) = f2bu(sqrtf(n2B[e]));
            }
        }
        if (xv) {
            f32x4 n2A = zero4(), n2B = zero4();
#pragma unroll
            for (int d = 0; d < 3; ++d) {
                f32x4 aA = zero4(), aB = zero4();
#pragma unroll
                for (int kt = 0; kt < 4; ++kt) {
                    const int k0 = kt * 32 + lg * 8;
                    bf16x8 a = afrag(Lsx + VIN_OFF + (d << 12), 256, l15, (kt << 6) + (lg << 4));
                    aA = MF(a, bfragb(v1wB, 128, gA, k0), aA);
                    aB = MF(a, bfragb(v1wB, 128, gB, k0), aB);
                }
#pragma unroll
                for (int e = 0; e < 4; ++e) {
                    float xA = aA[e] + 1e-8f; n2A[e] += xA * xA;
                    float xB = aB[e] + 1e-8f; n2B[e] += xB * xB;
                }
            }
#pragma unroll
            for (int e = 0; e < 4; ++e) {
                int row = (lg << 2) + e, swz = (row & 7) << 4;
                *(unsigned short*)(Lsx + H_OFF + row * 512 + ((256 + (gA << 1)) ^ swz)) = f2bu(sqrtf(n2A[e]));
                *(unsigned short*)(Lsx + H_OFF + row * 512 + ((256 + (gB << 1)) ^ swz)) = f2bu(sqrtf(n2B[e]));
            }
        }
        __syncthreads();

        // ======== slot 2: Y.P2 (L0 MLP1) || X.P5 (L1 MLP1 + folded readout) ; write V(Z) ========
        if (yv) {
            f32x4 mA = zero4(), mB = zero4();
#pragma unroll
            for (int kt = 0; kt < 8; ++kt) {
                const int k0 = kt * 32 + lg * 8;
                bf16x8 a = afrag(Lsy + H_OFF, 512, l15, (kt << 6) + (lg << 4));
                mA = MF(a, bfragb(w1f0B, 256, gA, k0), mA);
                mB = MF(a, bfragb(w1f0B, 256, gB, k0), mB);
            }
#pragma unroll
            for (int e = 0; e < 4; ++e) {
                int row = (lg << 2) + e, swz = (row & 7) << 4;
                float xA = mA[e] + b1_0A, xB = mB[e] + b1_0B;
                *(unsigned short*)(lds + S1_OFF + row * 256 + ((gA << 1) ^ swz)) = f2bu(xA / (1.f + __expf(-xA)));
                *(unsigned short*)(lds + S1_OFF + row * 256 + ((gB << 1) ^ swz)) = f2bu(xB / (1.f + __expf(-xB)));
            }
        }
        if (xv) {
            f32x4 mA = zero4(), mB = zero4();
#pragma unroll
            for (int kt = 0; kt < 8; ++kt) {
                const int k0 = kt * 32 + lg * 8;
                bf16x8 a = afrag(Lsx + H_OFF, 512, l15, (kt << 6) + (lg << 4));
                mA = MF(a, bfragb(w1f1B, 256, gA, k0), mA);
                mB = MF(a, bfragb(w1f1B, 256, gB, k0), mB);
            }
            float pA[4], pB[4];
#pragma unroll
            for (int e = 0; e < 4; ++e) {
                float xA = mA[e] + b1_1A, xB = mB[e] + b1_1B;
                pA[e] = (xA / (1.f + __expf(-xA))) * wfA;
                pB[e] = (xB / (1.f + __expf(-xB))) * wfB;
            }
#pragma unroll
            for (int off = 1; off < 16; off <<= 1) {
#pragma unroll
                for (int e = 0; e < 4; ++e) {
                    pA[e] += __shfl_xor(pA[e], off);
                    pB[e] += __shfl_xor(pB[e], off);
                }
            }
            if (l15 == 0) {
#pragma unroll
                for (int e = 0; e < 4; ++e) {
                    red[((wv << 1) + 0) * 16 + (lg << 2) + e] = pA[e];
                    red[((wv << 1) + 1) * 16 + (lg << 2) + e] = pB[e];
                }
            }
        }
        if (zv) write_v6(Lsx, tid, vldZ);
        __syncthreads();

        // ======== slot 3: Y.P3 (L0 MLP2 + v'=v1*ss) ; write S(Z) ; sOut(X) ========
        if (yv) {
            f32x4 sgA = zero4(), sgB = zero4(), ssA = zero4(), ssB = zero4();
#pragma unroll
            for (int kt = 0; kt < 4; ++kt) {
                const int k0 = kt * 32 + lg * 8;
                bf16x8 a = afrag(lds + S1_OFF, 256, l15, (kt << 6) + (lg << 4));
                sgA = MF(a, bfragb(w2gB, 128, gA, k0), sgA);
                sgB = MF(a, bfragb(w2gB, 128, gB, k0), sgB);
                ssA = MF(a, bfragb(w2sB, 128, gA, k0), ssA);
                ssB = MF(a, bfragb(w2sB, 128, gB, k0), ssB);
            }
#pragma unroll
            for (int e = 0; e < 4; ++e) {
                int row = (lg << 2) + e, swz = (row & 7) << 4;
                *(unsigned short*)(Lsy + H_OFF + row * 512 + ((gA << 1) ^ swz)) = f2bu(sgA[e] + b2g0A);
                *(unsigned short*)(Lsy + H_OFF + row * 512 + ((gB << 1) ^ swz)) = f2bu(sgB[e] + b2g0B);
                float ssvA = ssA[e] + b2s0A, ssvB = ssB[e] + b2s0B;
#pragma unroll
                for (int d = 0; d < 3; ++d) {
                    *(unsigned short*)(Lsy + VIN_OFF + (d << 12) + row * 256 + ((gA << 1) ^ swz)) =
                        f2bu(v1aA[d][e] * ssvA);
                    *(unsigned short*)(Lsy + VIN_OFF + (d << 12) + row * 256 + ((gB << 1) ^ swz)) =
                        f2bu(v1aB[d][e] * ssvB);
                }
            }
        }
        if (zv) write_s2(Lsx, tid, sldZ);
        if (xv && tid < 16) {
            float s = 0.f;
#pragma unroll
            for (int g = 0; g < 8; ++g) s += red[g * 16 + tid];
            sOut[((ty - stride) << 4) + tid] = s + cf;
        }
        __syncthreads();
    }
}

// Dense masked pooling: y[b] = sum_a batch[b,a] * s_out[a]
__global__ __launch_bounds__(256) void eqsc_pool(const float* __restrict__ batch,
                                                 const float* __restrict__ s,
                                                 float* __restrict__ out,
                                                 int NA, int B, int CH)
{
    int b  = blockIdx.x % B;
    int ch = blockIdx.x / B;
    int a0 = ch * CH;
    int a1 = min(a0 + CH, NA);
    const float* br = batch + (size_t)b * NA;
    float acc = 0.f;
    for (int a = a0 + (threadIdx.x << 2); a < a1; a += 256 * 4) {
        f32x4 bb = *(const f32x4*)(br + a);
        f32x4 sv = *(const f32x4*)(s + a);
        acc += bb[0] * sv[0] + bb[1] * sv[1] + bb[2] * sv[2] + bb[3] * sv[3];
    }
#pragma unroll
    for (int off = 32; off > 0; off >>= 1) acc += __shfl_down(acc, off);
    __shared__ float wsum[4];
    if ((threadIdx.x & 63) == 0) wsum[threadIdx.x >> 6] = acc;
    __syncthreads();
    if (threadIdx.x == 0) atomicAdd(&out[b], wsum[0] + wsum[1] + wsum[2] + wsum[3]);
}

extern "C" void kernel_launch(void* const* d_in, const int* in_sizes, int n_in,
                              void* d_out, int out_size, void* d_ws, size_t ws_size,
                              hipStream_t stream)
{
    const float* S     = (const float*)d_in[0];
    const float* V     = (const float*)d_in[1];
    // d_in[2] = pos, unused by the reference
    const float* batch = (const float*)d_in[3];
    const float* u0w   = (const float*)d_in[4];
    const float* v0w   = (const float*)d_in[5];
    const float* a0w1  = (const float*)d_in[6];
    const float* a0b1  = (const float*)d_in[7];
    const float* a0w2  = (const float*)d_in[8];
    const float* a0b2  = (const float*)d_in[9];
    const float* u1w   = (const float*)d_in[10];
    const float* v1w   = (const float*)d_in[11];
    const float* a1w1  = (const float*)d_in[12];
    const float* a1b1  = (const float*)d_in[13];
    const float* a1w2  = (const float*)d_in[14];
    const float* a1b2  = (const float*)d_in[15];
    const float* outw  = (const float*)d_in[16];
    const float* outb  = (const float*)d_in[17];
    (void)u1w;

    const int NA = in_sizes[0] / 128;
    const int NT = NA / 16;                  // 16 atoms per tile
    const int B  = in_sizes[3] / NA;

    unsigned short* wbuf = (unsigned short*)d_ws;
    float* wfold = (float*)((char*)d_ws + WFOLD_BYTE);
    float* cfp   = (float*)((char*)d_ws + CF_BYTE);
    float* sAtom = (float*)((char*)d_ws + SATOM_BYTE);

    hipMemsetAsync(d_out, 0, (size_t)out_size * sizeof(float), stream);

    // prep: 147456 weight elems -> bf16, + folded readout (576*256 = 147456)
    eqsc_prep<<<576, 256, 0, stream>>>(u0w, v0w, a0w2, v1w, a0w1, a1w1,
                                       a1w2, outw, a1b2, outb, wbuf, wfold, cfp);

    // main: 256-thr blocks, <=170 regs -> 3 blocks/CU (12 waves/CU), LDS 3*45.5KB
    eqsc_main<<<768, 256, 0, stream>>>(S, V, wbuf, wfold, cfp,
                                       a0b1, a0b2, a1b1, sAtom, NT);

    const int CH  = 16384;
    const int NCH = (NA + CH - 1) / CH;
    eqsc_pool<<<B * NCH, 256, 0, stream>>>(batch, sAtom, (float*)d_out, NA, B, CH);
}

// Round 11
// 244.303 us; speedup vs baseline: 2.8586x; 2.8586x over previous
//
#include <hip/hip_runtime.h>
#include <hip/hip_bf16.h>
#include <math.h>

typedef __attribute__((ext_vector_type(4))) float  f32x4;
typedef __attribute__((ext_vector_type(8))) __bf16 bf16x8;
typedef __attribute__((ext_vector_type(4))) unsigned int u32x4;

__device__ __forceinline__ f32x4 MF(bf16x8 a, bf16x8 b, f32x4 c) {
    return __builtin_amdgcn_mfma_f32_16x16x32_bf16(a, b, c, 0, 0, 0);
}

__device__ __forceinline__ f32x4 zero4() { f32x4 z = {0.f, 0.f, 0.f, 0.f}; return z; }

// packed f32->bf16 (RNE), 2 elems/instr
__device__ __forceinline__ unsigned int pkbf(float lo, float hi) {
    unsigned int r;
    asm("v_cvt_pk_bf16_f32 %0, %1, %2" : "=v"(r) : "v"(lo), "v"(hi));
    return r;
}
__device__ __forceinline__ unsigned long long pk4(f32x4 x) {
    return (unsigned long long)pkbf(x[0], x[1]) | ((unsigned long long)pkbf(x[2], x[3]) << 32);
}

__device__ __forceinline__ unsigned short f2bu(float x) {
    __bf16 h = (__bf16)x;
    return __builtin_bit_cast(unsigned short, h);
}

// B-fragment (BT row-major, contiguous K): lane holds BT[row][k0..k0+7], f32 -> bf16
__device__ __forceinline__ bf16x8 bfrag_g(const float* W, int ldk, int row, int k0) {
    const float* p = W + (size_t)row * ldk + k0;
    bf16x8 r;
#pragma unroll
    for (int e = 0; e < 8; ++e) r[e] = (__bf16)p[e];
    return r;
}

// ---- LDS layout (bytes), M=16 atoms/tile, two ping-pong sets ----
#define SET_SZ   20480
#define VIN_OFF  0        // 3 * 16 rows * 256B
#define H_OFF    12288    // 16 rows * 512B
#define S1_OFF   40960    // 16 rows * 256B
#define RED_OFF  45056    // 8 waves * 16 f32
#define LDS_BYTES 45568

// A-fragment read from swizzled LDS tile
__device__ __forceinline__ bf16x8 afrag(const unsigned char* base, int rb, int row, int kb) {
    u32x4 q = *(const u32x4*)(base + row * rb + (kb ^ ((row & 7) << 4)));
    return __builtin_bit_cast(bf16x8, q);
}

__global__ __launch_bounds__(512, 2) void eqsc_main(
    const float* __restrict__ S, const float* __restrict__ V,
    const float* __restrict__ u0w, const float* __restrict__ v0w,
    const float* __restrict__ a0w1, const float* __restrict__ a0b1,
    const float* __restrict__ a0w2, const float* __restrict__ a0b2,
    const float* __restrict__ u1w, const float* __restrict__ v1w,
    const float* __restrict__ a1w1, const float* __restrict__ a1b1,
    const float* __restrict__ a1w2, const float* __restrict__ a1b2,
    const float* __restrict__ outw, const float* __restrict__ outbp,
    float* __restrict__ sOut, int NT)
{
    __shared__ __align__(16) unsigned char lds[LDS_BYTES];
    const int tid  = threadIdx.x;
    const int lane = tid & 63;
    const int wv   = tid >> 6;
    const int l15  = lane & 15;
    const int lg   = lane >> 4;
    const int grow = wv * 16 + l15;   // weight-fragment row (output feature)
    const int kbb  = lg << 4;         // k-byte base within a 64B kt chunk
    const int fb0  = wv * 16 + (lg << 2);   // epilogue: this lane's 4-feature base
    const int erow = l15;                    // epilogue: this lane's atom row
    const int eswz = (erow & 7) << 4;

    // ---- folded readout (vector): wfv[e] = sum_g a1w2[g,fb0+e]*outw[g] ----
    f32x4 wfv = zero4();
    float cf = 0.f;
    for (int g = 0; g < 128; ++g) {
        float og = outw[g];
        f32x4 w4 = *(const f32x4*)(a1w2 + g * 128 + fb0);
#pragma unroll
        for (int e = 0; e < 4; ++e) wfv[e] += w4[e] * og;
        cf += a1b2[g] * og;
    }
    cf += outbp[0];

    // ---- persistent weight fragments (bf16): 144 regs ----
    bf16x8 uw0f[4], vw0f[4], w2g0[4], w2s0[4], vw1f[4];
    bf16x8 w1f0[8], w1f1[8];
#pragma unroll
    for (int kt = 0; kt < 4; ++kt) {
        int k0 = kt * 32 + lg * 8;
        uw0f[kt] = bfrag_g(u0w, 128, grow, k0);
        vw0f[kt] = bfrag_g(v0w, 128, grow, k0);
        w2g0[kt] = bfrag_g(a0w2, 128, grow, k0);
        w2s0[kt] = bfrag_g(a0w2, 128, 128 + grow, k0);
        vw1f[kt] = bfrag_g(v1w, 128, grow, k0);
    }
#pragma unroll
    for (int kt = 0; kt < 8; ++kt) {
        int k0 = kt * 32 + lg * 8;
        w1f0[kt] = bfrag_g(a0w1, 256, grow, k0);
        w1f1[kt] = bfrag_g(a1w1, 256, grow, k0);
    }
    const f32x4 b1_0v = *(const f32x4*)(a0b1 + fb0);
    const f32x4 b2g0v = *(const f32x4*)(a0b2 + fb0);
    const f32x4 b2s0v = *(const f32x4*)(a0b2 + 128 + fb0);
    const f32x4 b1_1v = *(const f32x4*)(a1b1 + fb0);

    const int stride = gridDim.x;
    const int t0 = blockIdx.x;

    // ---- prologue: stage tile t0 into set 0 ----
    if (t0 < NT) {
        f32x4 vld[3], sld;
#pragma unroll
        for (int j = 0; j < 3; ++j) {
            int c = tid + (j << 9);
            int d = c >> 9, rem = c & 511;
            int row = rem >> 5, c4 = rem & 31;
            vld[j] = *(const f32x4*)(V + (((size_t)((t0 << 4) + row) * 3 + d) << 7) + (c4 << 2));
        }
        { int row = tid >> 5, c4 = tid & 31;
          sld = *(const f32x4*)(S + (((size_t)((t0 << 4) + row)) << 7) + (c4 << 2)); }
#pragma unroll
        for (int j = 0; j < 3; ++j) {
            int c = tid + (j << 9);
            int d = c >> 9, rem = c & 511;
            int row = rem >> 5, c4 = rem & 31;
            *(unsigned long long*)(lds + VIN_OFF + (d << 12) + row * 256 +
                                   ((c4 << 3) ^ ((row & 7) << 4))) = pk4(vld[j]);
        }
        { int row = tid >> 5, c4 = tid & 31;
          *(unsigned long long*)(lds + H_OFF + row * 512 +
                                 ((c4 << 3) ^ ((row & 7) << 4))) = pk4(sld); }
    }
    __syncthreads();

    int i = 0;
    for (int ty = t0; ty < NT + stride; ty += stride, ++i) {
        const bool yv = (ty < NT);
        const bool xv = (i > 0);
        const int  tz = ty + stride;
        const bool zv = (tz < NT);
        unsigned char* Lsy = lds + (i & 1) * SET_SZ;
        unsigned char* Lsx = lds + ((i & 1) ^ 1) * SET_SZ;

        // ======== slot 1: Y.P1 (L0 v-GEMMs) || X.P4 (L1 v-GEMM) ; issue Z loads ========
        f32x4 vld[3], sld;
        if (zv) {
#pragma unroll
            for (int j = 0; j < 3; ++j) {
                int c = tid + (j << 9);
                int d = c >> 9, rem = c & 511;
                int row = rem >> 5, c4 = rem & 31;
                vld[j] = *(const f32x4*)(V + (((size_t)((tz << 4) + row) * 3 + d) << 7) + (c4 << 2));
            }
            { int row = tid >> 5, c4 = tid & 31;
              sld = *(const f32x4*)(S + (((size_t)((tz << 4) + row)) << 7) + (c4 << 2)); }
        }

        f32x4 v1a[3];
        if (yv) {
            f32x4 n2 = zero4();
#pragma unroll
            for (int d = 0; d < 3; ++d) {
                f32x4 a1 = zero4(), a2 = zero4();
#pragma unroll
                for (int kt = 0; kt < 4; ++kt) {
                    bf16x8 a = afrag(Lsy + VIN_OFF + (d << 12), 256, l15, (kt << 6) + kbb);
                    a1 = MF(uw0f[kt], a, a1);   // swapped: C = (col=atom, row=feature)
                    a2 = MF(vw0f[kt], a, a2);
                }
                v1a[d] = a1;
#pragma unroll
                for (int e = 0; e < 4; ++e) { float x = a2[e] + 1e-8f; n2[e] += x * x; }
            }
            f32x4 nr;
#pragma unroll
            for (int e = 0; e < 4; ++e) nr[e] = sqrtf(n2[e]);
            *(unsigned long long*)(Lsy + H_OFF + erow * 512 +
                ((256 + (fb0 << 1)) ^ eswz)) = pk4(nr);
        }
        if (xv) {
            f32x4 n2 = zero4();
#pragma unroll
            for (int d = 0; d < 3; ++d) {
                f32x4 acc = zero4();
#pragma unroll
                for (int kt = 0; kt < 4; ++kt)
                    acc = MF(vw1f[kt], afrag(Lsx + VIN_OFF + (d << 12), 256, l15, (kt << 6) + kbb),
                             acc);
#pragma unroll
                for (int e = 0; e < 4; ++e) { float x = acc[e] + 1e-8f; n2[e] += x * x; }
            }
            f32x4 nr;
#pragma unroll
            for (int e = 0; e < 4; ++e) nr[e] = sqrtf(n2[e]);
            *(unsigned long long*)(Lsx + H_OFF + erow * 512 +
                ((256 + (fb0 << 1)) ^ eswz)) = pk4(nr);
        }
        __syncthreads();

        // ======== slot 2: Y.P2 (L0 MLP1) || X.P5 (L1 MLP1 + folded readout) ; write V(Z) ========
        if (yv) {
            f32x4 m = zero4();
#pragma unroll
            for (int kt = 0; kt < 8; ++kt)
                m = MF(w1f0[kt], afrag(Lsy + H_OFF, 512, l15, (kt << 6) + kbb), m);
            f32x4 y;
#pragma unroll
            for (int e = 0; e < 4; ++e) {
                float x = m[e] + b1_0v[e];
                y[e] = x / (1.f + __expf(-x));
            }
            *(unsigned long long*)(lds + S1_OFF + erow * 256 +
                ((fb0 << 1) ^ eswz)) = pk4(y);
        }
        if (xv) {
            f32x4 m = zero4();
#pragma unroll
            for (int kt = 0; kt < 8; ++kt)
                m = MF(w1f1[kt], afrag(Lsx + H_OFF, 512, l15, (kt << 6) + kbb), m);
            float p = 0.f;
#pragma unroll
            for (int e = 0; e < 4; ++e) {
                float x = m[e] + b1_1v[e];
                p += (x / (1.f + __expf(-x))) * wfv[e];   // folded readout, f32
            }
            p += __shfl_xor(p, 16);
            p += __shfl_xor(p, 32);
            if (lane < 16)
                *((float*)(lds + RED_OFF) + (wv << 4) + lane) = p;
        }
        if (zv) {
#pragma unroll
            for (int j = 0; j < 3; ++j) {
                int c = tid + (j << 9);
                int d = c >> 9, rem = c & 511;
                int row = rem >> 5, c4 = rem & 31;
                *(unsigned long long*)(Lsx + VIN_OFF + (d << 12) + row * 256 +
                                       ((c4 << 3) ^ ((row & 7) << 4))) = pk4(vld[j]);
            }
        }
        __syncthreads();

        // ======== slot 3: Y.P3 (L0 MLP2 + v'=v1*ss) ; write S(Z) ; sOut(X) ========
        if (yv) {
            f32x4 sg = zero4(), ssa = zero4();
#pragma unroll
            for (int kt = 0; kt < 4; ++kt) {
                bf16x8 a = afrag(lds + S1_OFF, 256, l15, (kt << 6) + kbb);
                sg  = MF(w2g0[kt], a, sg);
                ssa = MF(w2s0[kt], a, ssa);
            }
            f32x4 g, ssv;
#pragma unroll
            for (int e = 0; e < 4; ++e) {
                g[e]   = sg[e] + b2g0v[e];
                ssv[e] = ssa[e] + b2s0v[e];
            }
            *(unsigned long long*)(Lsy + H_OFF + erow * 512 + ((fb0 << 1) ^ eswz)) = pk4(g);
#pragma unroll
            for (int d = 0; d < 3; ++d) {
                f32x4 vp;
#pragma unroll
                for (int e = 0; e < 4; ++e) vp[e] = v1a[d][e] * ssv[e];
                *(unsigned long long*)(Lsy + VIN_OFF + (d << 12) + erow * 256 +
                    ((fb0 << 1) ^ eswz)) = pk4(vp);
            }
        }
        if (zv) {
            int row = tid >> 5, c4 = tid & 31;
            *(unsigned long long*)(Lsx + H_OFF + row * 512 +
                                   ((c4 << 3) ^ ((row & 7) << 4))) = pk4(sld);
        }
        if (xv && tid < 16) {
            float s = 0.f;
#pragma unroll
            for (int w = 0; w < 8; ++w) s += *((float*)(lds + RED_OFF) + (w << 4) + tid);
            sOut[((ty - stride) << 4) + tid] = s + cf;
        }
        __syncthreads();
    }
}

// Dense masked pooling: y[b] = sum_a batch[b,a] * s_out[a]
__global__ __launch_bounds__(256) void eqsc_pool(const float* __restrict__ batch,
                                                 const float* __restrict__ s,
                                                 float* __restrict__ out,
                                                 int NA, int B, int CH)
{
    int b  = blockIdx.x % B;
    int ch = blockIdx.x / B;
    int a0 = ch * CH;
    int a1 = min(a0 + CH, NA);
    const float* br = batch + (size_t)b * NA;
    float acc = 0.f;
    for (int a = a0 + (threadIdx.x << 2); a < a1; a += 256 * 4) {
        f32x4 bb = *(const f32x4*)(br + a);
        f32x4 sv = *(const f32x4*)(s + a);
        acc += bb[0] * sv[0] + bb[1] * sv[1] + bb[2] * sv[2] + bb[3] * sv[3];
    }
#pragma unroll
    for (int off = 32; off > 0; off >>= 1) acc += __shfl_down(acc, off);
    __shared__ float wsum[4];
    if ((threadIdx.x & 63) == 0) wsum[threadIdx.x >> 6] = acc;
    __syncthreads();
    if (threadIdx.x == 0) atomicAdd(&out[b], wsum[0] + wsum[1] + wsum[2] + wsum[3]);
}

extern "C" void kernel_launch(void* const* d_in, const int* in_sizes, int n_in,
                              void* d_out, int out_size, void* d_ws, size_t ws_size,
                              hipStream_t stream)
{
    const float* S     = (const float*)d_in[0];
    const float* V     = (const float*)d_in[1];
    // d_in[2] = pos, unused by the reference
    const float* batch = (const float*)d_in[3];
    const float* u0w   = (const float*)d_in[4];
    const float* v0w   = (const float*)d_in[5];
    const float* a0w1  = (const float*)d_in[6];
    const float* a0b1  = (const float*)d_in[7];
    const float* a0w2  = (const float*)d_in[8];
    const float* a0b2  = (const float*)d_in[9];
    const float* u1w   = (const float*)d_in[10];
    const float* v1w   = (const float*)d_in[11];
    const float* a1w1  = (const float*)d_in[12];
    const float* a1b1  = (const float*)d_in[13];
    const float* a1w2  = (const float*)d_in[14];
    const float* a1b2  = (const float*)d_in[15];
    const float* outw  = (const float*)d_in[16];
    const float* outb  = (const float*)d_in[17];

    const int NA = in_sizes[0] / 128;
    const int NT = NA / 16;                  // 16 atoms per tile
    const int B  = in_sizes[3] / NA;
    float* sAtom = (float*)d_ws;

    hipMemsetAsync(d_out, 0, (size_t)out_size * sizeof(float), stream);

    eqsc_main<<<256, 512, 0, stream>>>(S, V, u0w, v0w, a0w1, a0b1, a0w2, a0b2,
                                       u1w, v1w, a1w1, a1b1, a1w2, a1b2,
                                       outw, outb, sAtom, NT);

    const int CH  = 16384;
    const int NCH = (NA + CH - 1) / CH;
    eqsc_pool<<<B * NCH, 256, 0, stream>>>(batch, sAtom, (float*)d_out, NA, B, CH);
}